// Round 4
// baseline (65.987 us; speedup 1.0000x reference)
//
#include <hip/hip_runtime.h>
#include <float.h>

#define B_TOK 256
#define N_OUT 512
#define K_IN  1024

// Single fused kernel.
// Grid (32, 16) = 512 blocks (2/CU). Block tile: 8 b x 32 n = 256 outputs.
// Block = 512 threads = 8 waves; wave wv owns k-chunk [wv*128, wv*128+128).
// Lane: bb = ln>>3 (one b row), nq = ln&7 (one n-quad = 4 n rows).
// All operand reads from global/L1 with float4 along k (100% line efficiency,
// 8-lane address broadcast). Per-wave L1 working set: 32 w rows + 8 x rows
// = ~2.5KB of live lines. Wave partials combine once via 16KB LDS.
__global__ __launch_bounds__(512)
void mam_one(const float* __restrict__ x, const float* __restrict__ w,
             const float* __restrict__ bias, float* __restrict__ out) {
    const int tid = threadIdx.x;
    const int wv  = tid >> 6;          // 0..7  -> k-chunk
    const int ln  = tid & 63;
    const int nq  = ln & 7;            // n-quad within 32-n tile
    const int bb  = ln >> 3;           // 0..7  -> b row
    const int b0  = blockIdx.x * 8;
    const int n0  = blockIdx.y * 32;
    const int k0  = wv * 128;

    const float* xr  = x + (size_t)(b0 + bb) * K_IN + k0;
    const float* wr0 = w + (size_t)(n0 + nq * 4 + 0) * K_IN + k0;
    const float* wr1 = w + (size_t)(n0 + nq * 4 + 1) * K_IN + k0;
    const float* wr2 = w + (size_t)(n0 + nq * 4 + 2) * K_IN + k0;
    const float* wr3 = w + (size_t)(n0 + nq * 4 + 3) * K_IN + k0;

    // acc per n of the quad
    float mx0 = -FLT_MAX, mx1 = -FLT_MAX, mx2 = -FLT_MAX, mx3 = -FLT_MAX;
    float mn0 =  FLT_MAX, mn1 =  FLT_MAX, mn2 =  FLT_MAX, mn3 =  FLT_MAX;

#pragma unroll 2
    for (int kk = 0; kk < 128; kk += 4) {
        const float4 xv = *reinterpret_cast<const float4*>(xr  + kk);
        const float4 wa = *reinterpret_cast<const float4*>(wr0 + kk);
        const float4 wb = *reinterpret_cast<const float4*>(wr1 + kk);
        const float4 wc = *reinterpret_cast<const float4*>(wr2 + kk);
        const float4 wd = *reinterpret_cast<const float4*>(wr3 + kk);

        {   const float p0 = xv.x * wa.x, p1 = xv.y * wa.y, p2 = xv.z * wa.z, p3 = xv.w * wa.w;
            mx0 = fmaxf(fmaxf(mx0, p0), p1); mx0 = fmaxf(fmaxf(mx0, p2), p3);   // v_max3
            mn0 = fminf(fminf(mn0, p0), p1); mn0 = fminf(fminf(mn0, p2), p3); }
        {   const float p0 = xv.x * wb.x, p1 = xv.y * wb.y, p2 = xv.z * wb.z, p3 = xv.w * wb.w;
            mx1 = fmaxf(fmaxf(mx1, p0), p1); mx1 = fmaxf(fmaxf(mx1, p2), p3);
            mn1 = fminf(fminf(mn1, p0), p1); mn1 = fminf(fminf(mn1, p2), p3); }
        {   const float p0 = xv.x * wc.x, p1 = xv.y * wc.y, p2 = xv.z * wc.z, p3 = xv.w * wc.w;
            mx2 = fmaxf(fmaxf(mx2, p0), p1); mx2 = fmaxf(fmaxf(mx2, p2), p3);
            mn2 = fminf(fminf(mn2, p0), p1); mn2 = fminf(fminf(mn2, p2), p3); }
        {   const float p0 = xv.x * wd.x, p1 = xv.y * wd.y, p2 = xv.z * wd.z, p3 = xv.w * wd.w;
            mx3 = fmaxf(fmaxf(mx3, p0), p1); mx3 = fmaxf(fmaxf(mx3, p2), p3);
            mn3 = fminf(fminf(mn3, p0), p1); mn3 = fminf(fminf(mn3, p2), p3); }
    }

    // combine 8 wave-partials once via LDS: [kc][mx/mn][256 outputs]
    __shared__ float red[8][2][256];
    const int ob = bb * 32 + nq * 4;    // output base within tile (16B aligned)
    float4 vx = make_float4(mx0, mx1, mx2, mx3);
    float4 vn = make_float4(mn0, mn1, mn2, mn3);
    *reinterpret_cast<float4*>(&red[wv][0][ob]) = vx;
    *reinterpret_cast<float4*>(&red[wv][1][ob]) = vn;
    __syncthreads();

    if (tid < 256) {
        const int o  = tid;             // output within tile
        float MX = -FLT_MAX, MN = FLT_MAX;
#pragma unroll
        for (int c = 0; c < 8; ++c) {
            MX = fmaxf(MX, red[c][0][o]);
            MN = fminf(MN, red[c][1][o]);
        }
        const int b  = o >> 5;
        const int nl = o & 31;
        out[(size_t)(b0 + b) * N_OUT + n0 + nl] = MX + MN + bias[n0 + nl];
    }
}

extern "C" void kernel_launch(void* const* d_in, const int* in_sizes, int n_in,
                              void* d_out, int out_size, void* d_ws, size_t ws_size,
                              hipStream_t stream) {
    const float* x    = (const float*)d_in[0];   // [256,1024]
    const float* w    = (const float*)d_in[1];   // [512,1024]
    const float* bias = (const float*)d_in[2];   // [512]
    float* out = (float*)d_out;                  // [256,512] f32
    (void)d_ws; (void)ws_size;

    mam_one<<<dim3(B_TOK / 8, N_OUT / 32), 512, 0, stream>>>(x, w, bias, out);
}

// Round 5
// 19.581 us; speedup vs baseline: 3.3700x; 3.3700x over previous
//
#include <hip/hip_runtime.h>
#include <float.h>

#define B_TOK 256
#define N_OUT 512
#define K_IN  1024

#define KSPLIT 8
#define KC     (K_IN / KSPLIT)   // 128 k per block
#define BT     16                // b rows per block (4 per wave)
#define NT     64                // n per block (1 per lane)

// ---------------- Stage 1 ----------------
// grid (16 b-groups, 8 n-groups, 8 k-chunks) = 1024 blocks (4/CU); block 256 = 4 waves.
// w-tile [64 n][128 k] staged once into 32KB LDS (XOR-swizzled 16B chunks ->
// conflict-free ds_read_b128). x loads are readfirstlane-uniform -> scalar pipe.
// Lane = one n; wave = 4 b rows. Per 4k-iter: 1 ds_read_b128 + 4 uniform x loads
// feed 64 products (16 mul + 8 max3 + 8 min3).
__global__ __launch_bounds__(256)
void mam_stage1(const float* __restrict__ x, const float* __restrict__ w,
                float* __restrict__ pmx, float* __restrict__ pmn) {
    __shared__ float ws[NT * KC];   // 32 KB

    const int tid = threadIdx.x;
    const int b0  = blockIdx.x * BT;
    const int n0  = blockIdx.y * NT;
    const int kc  = blockIdx.z * KC;

    // ---- stage w[n0..n0+63][kc..kc+127] -> LDS, swizzled ----
    // thread t: row r = t>>2, chunks c = (t&3) + 4j (j=0..7): 4 consecutive lanes
    // read one contiguous 64B line. ds_write at chunk (c ^ (r&7)) spreads banks.
    {
        const int r  = tid >> 2;
        const int cb = tid & 3;
        const float* gsrc = w + (size_t)(n0 + r) * K_IN + kc;
#pragma unroll
        for (int j = 0; j < 8; ++j) {
            const int c = cb + 4 * j;
            const float4 v = *reinterpret_cast<const float4*>(gsrc + c * 4);
            *reinterpret_cast<float4*>(&ws[r * KC + ((c ^ (r & 7)) << 2)]) = v;
        }
    }
    __syncthreads();

    // ---- compute ----
    const int wv = __builtin_amdgcn_readfirstlane(tid >> 6);  // 0..3, SGPR
    const int ln = tid & 63;                                  // lane -> n
    const float* xb0 = x + (size_t)(b0 + wv * 4 + 0) * K_IN + kc;  // uniform
    const float* xb1 = x + (size_t)(b0 + wv * 4 + 1) * K_IN + kc;
    const float* xb2 = x + (size_t)(b0 + wv * 4 + 2) * K_IN + kc;
    const float* xb3 = x + (size_t)(b0 + wv * 4 + 3) * K_IN + kc;

    float mx0 = -FLT_MAX, mx1 = -FLT_MAX, mx2 = -FLT_MAX, mx3 = -FLT_MAX;
    float mn0 =  FLT_MAX, mn1 =  FLT_MAX, mn2 =  FLT_MAX, mn3 =  FLT_MAX;

    const int swz = ln & 7;
#pragma unroll 4
    for (int c = 0; c < KC / 4; ++c) {            // 32 iters of 4 k
        const float4 wk = *reinterpret_cast<const float4*>(
            &ws[ln * KC + ((c ^ swz) << 2)]);     // conflict-free b128
        const float4 x0 = *reinterpret_cast<const float4*>(xb0 + c * 4);
        const float4 x1 = *reinterpret_cast<const float4*>(xb1 + c * 4);
        const float4 x2 = *reinterpret_cast<const float4*>(xb2 + c * 4);
        const float4 x3 = *reinterpret_cast<const float4*>(xb3 + c * 4);

        {   const float p0 = x0.x * wk.x, p1 = x0.y * wk.y, p2 = x0.z * wk.z, p3 = x0.w * wk.w;
            mx0 = fmaxf(fmaxf(mx0, p0), p1); mx0 = fmaxf(fmaxf(mx0, p2), p3);
            mn0 = fminf(fminf(mn0, p0), p1); mn0 = fminf(fminf(mn0, p2), p3); }
        {   const float p0 = x1.x * wk.x, p1 = x1.y * wk.y, p2 = x1.z * wk.z, p3 = x1.w * wk.w;
            mx1 = fmaxf(fmaxf(mx1, p0), p1); mx1 = fmaxf(fmaxf(mx1, p2), p3);
            mn1 = fminf(fminf(mn1, p0), p1); mn1 = fminf(fminf(mn1, p2), p3); }
        {   const float p0 = x2.x * wk.x, p1 = x2.y * wk.y, p2 = x2.z * wk.z, p3 = x2.w * wk.w;
            mx2 = fmaxf(fmaxf(mx2, p0), p1); mx2 = fmaxf(fmaxf(mx2, p2), p3);
            mn2 = fminf(fminf(mn2, p0), p1); mn2 = fminf(fminf(mn2, p2), p3); }
        {   const float p0 = x3.x * wk.x, p1 = x3.y * wk.y, p2 = x3.z * wk.z, p3 = x3.w * wk.w;
            mx3 = fmaxf(fmaxf(mx3, p0), p1); mx3 = fmaxf(fmaxf(mx3, p2), p3);
            mn3 = fminf(fminf(mn3, p0), p1); mn3 = fminf(fminf(mn3, p2), p3); }
    }

    // ---- write one partial plane per k-chunk (coalesced 256B per row) ----
    const size_t plane = (size_t)B_TOK * N_OUT;
    const size_t base  = (size_t)blockIdx.z * plane
                       + (size_t)(b0 + wv * 4) * N_OUT + n0 + ln;
    pmx[base + 0 * N_OUT] = mx0;  pmn[base + 0 * N_OUT] = mn0;
    pmx[base + 1 * N_OUT] = mx1;  pmn[base + 1 * N_OUT] = mn1;
    pmx[base + 2 * N_OUT] = mx2;  pmn[base + 2 * N_OUT] = mn2;
    pmx[base + 3 * N_OUT] = mx3;  pmn[base + 3 * N_OUT] = mn3;
}

// ---------------- Stage 2: combine 8 planes + bias ----------------
__global__ __launch_bounds__(256)
void mam_stage2(const float* __restrict__ pmx, const float* __restrict__ pmn,
                const float* __restrict__ bias, float* __restrict__ out) {
    const size_t i4 = ((size_t)blockIdx.x * 256 + threadIdx.x) * 4;
    const size_t plane = (size_t)B_TOK * N_OUT;
    float4 MX = *reinterpret_cast<const float4*>(pmx + i4);
    float4 MN = *reinterpret_cast<const float4*>(pmn + i4);
#pragma unroll
    for (int p = 1; p < KSPLIT; ++p) {
        const float4 a = *reinterpret_cast<const float4*>(pmx + (size_t)p * plane + i4);
        const float4 i = *reinterpret_cast<const float4*>(pmn + (size_t)p * plane + i4);
        MX.x = fmaxf(MX.x, a.x); MX.y = fmaxf(MX.y, a.y);
        MX.z = fmaxf(MX.z, a.z); MX.w = fmaxf(MX.w, a.w);
        MN.x = fminf(MN.x, i.x); MN.y = fminf(MN.y, i.y);
        MN.z = fminf(MN.z, i.z); MN.w = fminf(MN.w, i.w);
    }
    const float4 bb = *reinterpret_cast<const float4*>(bias + (i4 & (N_OUT - 1)));
    float4 o;
    o.x = MX.x + MN.x + bb.x; o.y = MX.y + MN.y + bb.y;
    o.z = MX.z + MN.z + bb.z; o.w = MX.w + MN.w + bb.w;
    *reinterpret_cast<float4*>(out + i4) = o;
}

// ---------------- Fallback (workspace too small) ----------------
__global__ __launch_bounds__(256)
void mam_simple(const float* __restrict__ x, const float* __restrict__ w,
                const float* __restrict__ bias, float* __restrict__ out) {
    const int idx = blockIdx.x * 256 + threadIdx.x;
    const int b = idx / N_OUT, n = idx % N_OUT;
    const float* xr = x + (size_t)b * K_IN;
    const float* wr = w + (size_t)n * K_IN;
    float mx = -FLT_MAX, mn = FLT_MAX;
#pragma unroll 4
    for (int k = 0; k < K_IN; k += 4) {
        const float4 xv = *reinterpret_cast<const float4*>(xr + k);
        const float4 wv = *reinterpret_cast<const float4*>(wr + k);
        const float p0 = xv.x * wv.x, p1 = xv.y * wv.y;
        const float p2 = xv.z * wv.z, p3 = xv.w * wv.w;
        mx = fmaxf(fmaxf(mx, p0), p1);
        mx = fmaxf(fmaxf(mx, p2), p3);
        mn = fminf(fminf(mn, p0), p1);
        mn = fminf(fminf(mn, p2), p3);
    }
    out[idx] = mx + mn + bias[n];
}

extern "C" void kernel_launch(void* const* d_in, const int* in_sizes, int n_in,
                              void* d_out, int out_size, void* d_ws, size_t ws_size,
                              hipStream_t stream) {
    const float* x    = (const float*)d_in[0];   // [256,1024]
    const float* w    = (const float*)d_in[1];   // [512,1024]
    const float* bias = (const float*)d_in[2];   // [512]
    float* out = (float*)d_out;                  // [256,512] f32

    const size_t plane = (size_t)B_TOK * N_OUT;
    const size_t need  = 2 * (size_t)KSPLIT * plane * sizeof(float);  // 8 MB

    if (ws_size >= need) {
        float* pmx = (float*)d_ws;
        float* pmn = pmx + (size_t)KSPLIT * plane;
        mam_stage1<<<dim3(B_TOK / BT, N_OUT / NT, KSPLIT), 256, 0, stream>>>(x, w, pmx, pmn);
        mam_stage2<<<(int)(plane / 4 / 256), 256, 0, stream>>>(pmx, pmn, bias, out);
    } else {
        mam_simple<<<(B_TOK * N_OUT) / 256, 256, 0, stream>>>(x, w, bias, out);
    }
}